// Round 1
// baseline (547.673 us; speedup 1.0000x reference)
//
#include <hip/hip_runtime.h>
#include <math.h>

// Problem constants (fixed by the reference file)
#define T_ 256
#define N_ 64
#define C_ 4096
#define L_ 32
#define SL_ 33            // compact lp slots per (n,t): 0 = blank, 1+l = label l
#define NEGV (-1e30f)

// logaddexp matching jnp.logaddexp: max + log1p(exp(-|a-b|)).
// Both NEGV: |a-b|=0 -> NEGV + ln2 == NEGV in fp32 (absorbed). One NEGV:
// exp(-huge)=0 -> returns the finite max. Matches reference masking semantics.
__device__ __forceinline__ float lae(float a, float b) {
    float m = fmaxf(a, b);
    float d = fabsf(a - b);
    return m + log1pf(__expf(-d));
}

__device__ __forceinline__ float wred_max(float v) {
    #pragma unroll
    for (int o = 32; o > 0; o >>= 1) v = fmaxf(v, __shfl_xor(v, o));
    return v;
}
__device__ __forceinline__ float wred_sum(float v) {
    #pragma unroll
    for (int o = 32; o > 0; o >>= 1) v += __shfl_xor(v, o);
    return v;
}

// Kernel 1 (memory-bound, 268 MB): per (t,n) row of C=4096, compute
// log-sum-exp, then emit only the 33 needed log-probs (blank + L labels).
__global__ __launch_bounds__(256) void k_row_lse(
        const float* __restrict__ preds, const int* __restrict__ targets,
        float* __restrict__ lp) {
    const int bid = blockIdx.x;            // bid = t*N_ + n (preds row index)
    const int n   = bid & (N_ - 1);
    const int tid = threadIdx.x;
    const float* row = preds + (size_t)bid * C_;

    // Issue the gather loads early; they're independent of the reduction.
    float gv = 0.f;
    if (tid < SL_) {
        const int cls = (tid == 0) ? 0 : targets[n * L_ + (tid - 1)];
        gv = row[cls];
    }

    // 4096 floats / 256 threads = 16 each, as 4x float4 (coalesced).
    float4 v[4];
    #pragma unroll
    for (int k = 0; k < 4; ++k) v[k] = ((const float4*)row)[tid + k * 256];

    float m = v[0].x;
    #pragma unroll
    for (int k = 0; k < 4; ++k)
        m = fmaxf(m, fmaxf(fmaxf(v[k].x, v[k].y), fmaxf(v[k].z, v[k].w)));
    m = wred_max(m);

    __shared__ float red[8];
    const int wave = tid >> 6, lane = tid & 63;
    if (lane == 0) red[wave] = m;
    __syncthreads();
    const float M = fmaxf(fmaxf(red[0], red[1]), fmaxf(red[2], red[3]));

    float s = 0.f;
    #pragma unroll
    for (int k = 0; k < 4; ++k)
        s += __expf(v[k].x - M) + __expf(v[k].y - M)
           + __expf(v[k].z - M) + __expf(v[k].w - M);
    s = wred_sum(s);
    if (lane == 0) red[4 + wave] = s;      // slots 4..7 disjoint from 0..3
    __syncthreads();
    const float lse = M + __logf(red[4] + red[5] + red[6] + red[7]);

    if (tid < SL_) {
        const int t = bid >> 6;            // bid / N_
        lp[((size_t)n * T_ + t) * SL_ + tid] = gv - lse;
    }
}

// Kernel 2 (latency-bound scan): one block per batch item. Waves 1..3 help
// stage lp into LDS then exit; wave 0 runs the T-step alpha recursion with
// lane s owning state s (lane 63 also owns state 64 = blank, which never
// takes the skip transition, so its inputs alpha[63], alpha[64] are local).
__global__ __launch_bounds__(256) void k_ctc_scan(
        const float* __restrict__ lp, const int* __restrict__ targets,
        const int* __restrict__ plen, const int* __restrict__ tlen,
        float* __restrict__ partial) {
    __shared__ __align__(16) float lds[T_ * SL_];   // 33 KB
    const int n = blockIdx.x;
    const int tid = threadIdx.x;
    const float4* src = (const float4*)(lp + (size_t)n * T_ * SL_);
    float4* dst = (float4*)lds;
    for (int i = tid; i < (T_ * SL_) / 4; i += 256) dst[i] = src[i];
    __syncthreads();
    if (tid >= 64) return;                 // no further barriers

    const int lane = tid;
    const int tl = tlen[n];
    const int pl = plen[n];
    const int ends = 2 * tl;
    const bool odd = (lane & 1);
    const int slot   = odd ? 1 + (lane >> 1) : 0;
    const int cls    = odd ? targets[n * L_ + (lane >> 1)] : 0;
    const int clsm2  = (odd && lane >= 2) ? targets[n * L_ + (lane >> 1) - 1] : 0;
    const bool skip  = odd && (lane >= 2) && (cls != 0) && (cls != clsm2);
    const bool valid   = lane < 2 * tl + 1;
    const bool valid64 = (2 * tl + 1) > 64;    // is state 64 valid

    // alpha0: only s=0 (blank) and s=1 (first label, if tl>0) are live.
    float a = NEGV, b = NEGV;                  // a = alpha[lane], b = alpha[64] (lane 63)
    if (lane == 0) a = lds[0];
    if (lane == 1 && tl > 0) a = lds[1];

    for (int t = 1; t < T_; ++t) {
        // LDS reads: odd lanes hit slots 1..32 (32 distinct banks), even
        // lanes broadcast slot 0 -> conflict-free.
        const float lp_s = lds[t * SL_ + slot];
        const float lp64 = lds[t * SL_];       // blank lp (broadcast)
        const float up1 = __shfl_up(a, 1);
        const float up2 = __shfl_up(a, 2);
        const float a2 = (lane >= 1) ? up1 : NEGV;
        const float a3 = skip ? up2 : NEGV;
        const float comb = lae(lae(a, a2), a3);
        // state 64 (computed on every lane; only lane 63's value is read):
        const float nb = valid64 ? (lae(b, a) + lp64) : NEGV;
        const float na = valid ? (comb + lp_s) : NEGV;
        if (t < pl) { a = na; b = nb; }        // wave-uniform predicate
    }

    const float a_last = (ends >= 64) ? __shfl(b, 63) : __shfl(a, ends);
    float a_prev = __shfl(a, (ends > 0) ? (ends - 1) : 0);
    if (tl <= 0) a_prev = NEGV;
    float nll = -lae(a_last, a_prev);
    if (!(isfinite(nll) && nll < 1e29f)) nll = 0.f;
    if (lane == 0) partial[n] = nll / (float)((tl > 0) ? tl : 1);
}

// Kernel 3: mean over N=64 partials (one wave).
__global__ void k_mean(const float* __restrict__ partial, float* __restrict__ out) {
    float v = partial[threadIdx.x];
    v = wred_sum(v);
    if (threadIdx.x == 0) out[0] = v * (1.0f / (float)N_);
}

extern "C" void kernel_launch(void* const* d_in, const int* in_sizes, int n_in,
                              void* d_out, int out_size, void* d_ws, size_t ws_size,
                              hipStream_t stream) {
    const float* preds   = (const float*)d_in[0];
    const int*   targets = (const int*)d_in[1];
    const int*   plen    = (const int*)d_in[2];
    const int*   tlen    = (const int*)d_in[3];

    float* lp      = (float*)d_ws;                    // N*T*33 floats = 2.16 MB
    float* partial = lp + (size_t)N_ * T_ * SL_;      // +64 floats

    k_row_lse<<<T_ * N_, 256, 0, stream>>>(preds, targets, lp);
    k_ctc_scan<<<N_, 256, 0, stream>>>(lp, targets, plen, tlen, partial);
    k_mean<<<1, 64, 0, stream>>>(partial, (float*)d_out);
}

// Round 2
// 402.245 us; speedup vs baseline: 1.3615x; 1.3615x over previous
//
#include <hip/hip_runtime.h>
#include <math.h>

// Problem constants (fixed by the reference file)
#define T_ 256
#define N_ 64
#define C_ 4096
#define L_ 32
#define SL_ 33            // compact lp slots per (n,t): 0 = blank, 1+l = label l
#define NEGV (-1e30f)

// logaddexp via hardware transcendentals (v_exp_f32/v_log_f32).
// Accuracy ~1e-6 relative; test threshold is 1.27 absolute.
__device__ __forceinline__ float lae2(float a, float b) {
    float m = fmaxf(a, b);
    // if both NEG: exp(0)+exp(0)=2 -> m+ln2, absorbed by |NEG|.
    return m + __logf(__expf(a - m) + __expf(b - m));
}

// whole-wave shift-toward-higher-lane by 1 via DPP (wave_shr:1 = 0x138).
// Lane 0 receives `fill` (bound_ctrl=0 keeps `old` for invalid lanes).
__device__ __forceinline__ float dpp_shr1(float x, float fill) {
    int r = __builtin_amdgcn_update_dpp(__float_as_int(fill), __float_as_int(x),
                                        0x138, 0xF, 0xF, false);
    return __int_as_float(r);
}

__device__ __forceinline__ float wred_max(float v) {
    #pragma unroll
    for (int o = 32; o > 0; o >>= 1) v = fmaxf(v, __shfl_xor(v, o));
    return v;
}
__device__ __forceinline__ float wred_sum(float v) {
    #pragma unroll
    for (int o = 32; o > 0; o >>= 1) v += __shfl_xor(v, o);
    return v;
}

// Kernel 1 (memory-bound, 268 MB): per (t,n) row of C=4096, compute
// log-sum-exp, then emit only the 33 needed log-probs (blank + L labels).
__global__ __launch_bounds__(256) void k_row_lse(
        const float* __restrict__ preds, const int* __restrict__ targets,
        float* __restrict__ lp) {
    const int bid = blockIdx.x;            // bid = t*N_ + n (preds row index)
    const int n   = bid & (N_ - 1);
    const int tid = threadIdx.x;
    const float* row = preds + (size_t)bid * C_;

    // Issue the gather loads early; they're independent of the reduction.
    float gv = 0.f;
    if (tid < SL_) {
        const int cls = (tid == 0) ? 0 : targets[n * L_ + (tid - 1)];
        gv = row[cls];
    }

    // 4096 floats / 256 threads = 16 each, as 4x float4 (coalesced).
    float4 v[4];
    #pragma unroll
    for (int k = 0; k < 4; ++k) v[k] = ((const float4*)row)[tid + k * 256];

    float m = v[0].x;
    #pragma unroll
    for (int k = 0; k < 4; ++k)
        m = fmaxf(m, fmaxf(fmaxf(v[k].x, v[k].y), fmaxf(v[k].z, v[k].w)));
    m = wred_max(m);

    __shared__ float red[8];
    const int wave = tid >> 6, lane = tid & 63;
    if (lane == 0) red[wave] = m;
    __syncthreads();
    const float M = fmaxf(fmaxf(red[0], red[1]), fmaxf(red[2], red[3]));

    float s = 0.f;
    #pragma unroll
    for (int k = 0; k < 4; ++k)
        s += __expf(v[k].x - M) + __expf(v[k].y - M)
           + __expf(v[k].z - M) + __expf(v[k].w - M);
    s = wred_sum(s);
    if (lane == 0) red[4 + wave] = s;      // slots 4..7 disjoint from 0..3
    __syncthreads();
    const float lse = M + __logf(red[4] + red[5] + red[6] + red[7]);

    if (tid < SL_) {
        const int t = bid >> 6;            // bid / N_
        lp[((size_t)n * T_ + t) * SL_ + tid] = gv - lse;
    }
}

// Kernel 2 (latency-bound scan): one block per batch item. Waves 1..3 help
// stage lp into LDS then exit; wave 0 runs the T-step alpha recursion with
// lane s owning state s (lane 63 also owns state 64 = blank, which never
// takes the skip transition, so its inputs alpha[63], alpha[64] are local).
// Per-step critical path: 2x DPP lane-shift + one 3-way LSE on hardware
// transcendentals (~50 cyc) — no ds_bpermute, no libm log1pf.
__global__ __launch_bounds__(256) void k_ctc_scan(
        const float* __restrict__ lp, const int* __restrict__ targets,
        const int* __restrict__ plen, const int* __restrict__ tlen,
        float* __restrict__ partial) {
    // +SL_ padding so the t+1 prefetch on the last iteration stays in bounds.
    __shared__ __align__(16) float lds[(T_ + 1) * SL_];
    const int n = blockIdx.x;
    const int tid = threadIdx.x;
    const float4* src = (const float4*)(lp + (size_t)n * T_ * SL_);
    float4* dst = (float4*)lds;
    for (int i = tid; i < (T_ * SL_) / 4; i += 256) dst[i] = src[i];
    __syncthreads();
    if (tid >= 64) return;                 // no further barriers

    const int lane = tid;
    const int tl = tlen[n];
    const int pl = plen[n];
    const int ends = 2 * tl;
    const bool odd = (lane & 1);
    const int slot   = odd ? 1 + (lane >> 1) : 0;
    const int cls    = odd ? targets[n * L_ + (lane >> 1)] : 0;
    const int clsm2  = (odd && lane >= 2) ? targets[n * L_ + (lane >> 1) - 1] : 0;
    const bool skip  = odd && (lane >= 2) && (cls != 0) && (cls != clsm2);
    const bool valid   = lane < 2 * tl + 1;
    const bool valid64 = (2 * tl + 1) > 64;    // is state 64 valid

    // alpha0: only s=0 (blank) and s=1 (first label, if tl>0) are live.
    float a = NEGV, b = NEGV;                  // a = alpha[lane], b = alpha[64] (lane 63)
    if (lane == 0) a = lds[0];
    if (lane == 1 && tl > 0) a = lds[1];

    // Prefetch t=1 lp values; each iteration prefetches t+1 (pad makes the
    // final prefetch safe). Keeps lgkmcnt waits off the dependence chain.
    float lp_s  = lds[SL_ + slot];
    float lp64  = lds[SL_];

    for (int t = 1; t < T_; ++t) {
        const float lp_s_nxt = lds[(t + 1) * SL_ + slot];
        const float lp64_nxt = lds[(t + 1) * SL_];

        const float a2 = dpp_shr1(a, NEGV);              // alpha[lane-1]
        float a3 = dpp_shr1(a2, NEGV);                   // alpha[lane-2]
        a3 = skip ? a3 : NEGV;
        // 3-way logsumexp, one log on the chain:
        const float m3 = fmaxf(fmaxf(a, a2), a3);
        const float comb = m3 + __logf(__expf(a - m3) + __expf(a2 - m3)
                                       + __expf(a3 - m3));
        // state 64 (only lane 63's value is meaningful):
        const float nb = valid64 ? (lae2(b, a) + lp64) : NEGV;
        const float na = valid ? (comb + lp_s) : NEGV;
        if (t < pl) { a = na; b = nb; }        // wave-uniform predicate
        lp_s = lp_s_nxt; lp64 = lp64_nxt;
    }

    const float a_last = (ends >= 64) ? __shfl(b, 63) : __shfl(a, ends);
    float a_prev = __shfl(a, (ends > 0) ? (ends - 1) : 0);
    if (tl <= 0) a_prev = NEGV;
    float nll = -lae2(a_last, a_prev);
    if (!(isfinite(nll) && nll < 1e29f)) nll = 0.f;
    if (lane == 0) partial[n] = nll / (float)((tl > 0) ? tl : 1);
}

// Kernel 3: mean over N=64 partials (one wave).
__global__ void k_mean(const float* __restrict__ partial, float* __restrict__ out) {
    float v = partial[threadIdx.x];
    v = wred_sum(v);
    if (threadIdx.x == 0) out[0] = v * (1.0f / (float)N_);
}

extern "C" void kernel_launch(void* const* d_in, const int* in_sizes, int n_in,
                              void* d_out, int out_size, void* d_ws, size_t ws_size,
                              hipStream_t stream) {
    const float* preds   = (const float*)d_in[0];
    const int*   targets = (const int*)d_in[1];
    const int*   plen    = (const int*)d_in[2];
    const int*   tlen    = (const int*)d_in[3];

    float* lp      = (float*)d_ws;                    // N*T*33 floats = 2.16 MB
    float* partial = lp + (size_t)N_ * T_ * SL_;      // +64 floats

    k_row_lse<<<T_ * N_, 256, 0, stream>>>(preds, targets, lp);
    k_ctc_scan<<<N_, 256, 0, stream>>>(lp, targets, plen, tlen, partial);
    k_mean<<<1, 64, 0, stream>>>(partial, (float*)d_out);
}

// Round 3
// 396.863 us; speedup vs baseline: 1.3800x; 1.0136x over previous
//
#include <hip/hip_runtime.h>
#include <math.h>

// Problem constants (fixed by the reference file)
#define T_ 256
#define N_ 64
#define C_ 4096
#define L_ 32
#define SL_ 33            // compact lp slots per (n,t): 0 = blank, 1+l = label l
#define NEGV (-1e30f)

typedef float vf4 __attribute__((ext_vector_type(4)));

// logaddexp via hardware transcendentals (v_exp_f32/v_log_f32).
// Accuracy ~1e-6 relative; test threshold is 1.27 absolute.
__device__ __forceinline__ float lae2(float a, float b) {
    float m = fmaxf(a, b);
    // if both NEG: exp(0)+exp(0)=2 -> m+ln2, absorbed by |NEG|.
    return m + __logf(__expf(a - m) + __expf(b - m));
}

// whole-wave shift-toward-higher-lane by 1 via DPP (wave_shr:1 = 0x138).
// Lane 0 receives `fill` (bound_ctrl=0 keeps `old` for invalid lanes).
__device__ __forceinline__ float dpp_shr1(float x, float fill) {
    int r = __builtin_amdgcn_update_dpp(__float_as_int(fill), __float_as_int(x),
                                        0x138, 0xF, 0xF, false);
    return __int_as_float(r);
}

__device__ __forceinline__ float wred_max(float v) {
    #pragma unroll
    for (int o = 32; o > 0; o >>= 1) v = fmaxf(v, __shfl_xor(v, o));
    return v;
}
__device__ __forceinline__ float wred_sum(float v) {
    #pragma unroll
    for (int o = 32; o > 0; o >>= 1) v += __shfl_xor(v, o);
    return v;
}

// Kernel 1 (memory-bound, 268 MB): per (t,n) row of C=4096, compute
// log-sum-exp, then emit only the 33 needed log-probs (blank + L labels).
// Also zeroes the scan's completion counter (block 0) each launch.
__global__ __launch_bounds__(256) void k_row_lse(
        const float* __restrict__ preds, const int* __restrict__ targets,
        float* __restrict__ lp, int* __restrict__ counter) {
    const int bid = blockIdx.x;            // bid = t*N_ + n (preds row index)
    const int n   = bid & (N_ - 1);
    const int tid = threadIdx.x;
    if (bid == 0 && tid == 0) *counter = 0;   // ws is re-poisoned every launch
    const float* row = preds + (size_t)bid * C_;

    // Issue the gather loads early; they're independent of the reduction.
    float gv = 0.f;
    if (tid < SL_) {
        const int cls = (tid == 0) ? 0 : targets[n * L_ + (tid - 1)];
        gv = row[cls];
    }

    // 4096 floats / 256 threads = 16 each, as 4x float4, nontemporal
    // (pure streaming, no reuse -> don't pollute L2).
    const vf4* row4 = (const vf4*)row;
    vf4 v[4];
    #pragma unroll
    for (int k = 0; k < 4; ++k)
        v[k] = __builtin_nontemporal_load(&row4[tid + k * 256]);

    float m = v[0][0];
    #pragma unroll
    for (int k = 0; k < 4; ++k)
        m = fmaxf(m, fmaxf(fmaxf(v[k][0], v[k][1]), fmaxf(v[k][2], v[k][3])));
    m = wred_max(m);

    __shared__ float red[8];
    const int wave = tid >> 6, lane = tid & 63;
    if (lane == 0) red[wave] = m;
    __syncthreads();
    const float M = fmaxf(fmaxf(red[0], red[1]), fmaxf(red[2], red[3]));

    float s = 0.f;
    #pragma unroll
    for (int k = 0; k < 4; ++k)
        s += __expf(v[k][0] - M) + __expf(v[k][1] - M)
           + __expf(v[k][2] - M) + __expf(v[k][3] - M);
    s = wred_sum(s);
    if (lane == 0) red[4 + wave] = s;      // slots 4..7 disjoint from 0..3
    __syncthreads();
    const float lse = M + __logf(red[4] + red[5] + red[6] + red[7]);

    if (tid < SL_) {
        const int t = bid >> 6;            // bid / N_
        lp[((size_t)n * T_ + t) * SL_ + tid] = gv - lse;
    }
}

// Kernel 2 (latency-bound scan): one block per batch item. Waves 1..3 help
// stage lp into LDS then exit; wave 0 runs the T-step alpha recursion with
// lane s owning state s (lane 63 also owns state 64 = blank, which never
// takes the skip transition, so its inputs alpha[63], alpha[64] are local).
// LDS reads are prefetched 4 iterations ahead into a register ring
// (~130 cyc slack > ~120 cyc ds_read latency) so the per-step critical path
// is pure VALU + hw transcendentals (~35 cyc). The last block to finish also
// reduces the N partials to the final mean (saves the k_mean launch).
__global__ __launch_bounds__(256) void k_ctc_scan(
        const float* __restrict__ lp, const int* __restrict__ targets,
        const int* __restrict__ plen, const int* __restrict__ tlen,
        float* __restrict__ partial, int* __restrict__ counter,
        float* __restrict__ out) {
    // Pad: deepest prefetch index is (253+4+3)*SL_+32; (T_+16)*SL_ covers it.
    __shared__ __align__(16) float lds[(T_ + 16) * SL_];   // 35.9 KB
    const int n = blockIdx.x;
    const int tid = threadIdx.x;
    const vf4* src = (const vf4*)(lp + (size_t)n * T_ * SL_);
    vf4* dst = (vf4*)lds;
    for (int i = tid; i < (T_ * SL_) / 4; i += 256) dst[i] = src[i];
    __syncthreads();
    if (tid >= 64) return;                 // no further barriers

    const int lane = tid;
    const int tl = tlen[n];
    const int pl = plen[n];
    const int ends = 2 * tl;
    const bool odd = (lane & 1);
    const int slot   = odd ? 1 + (lane >> 1) : 0;
    const int cls    = odd ? targets[n * L_ + (lane >> 1)] : 0;
    const int clsm2  = (odd && lane >= 2) ? targets[n * L_ + (lane >> 1) - 1] : 0;
    const bool skip  = odd && (lane >= 2) && (cls != 0) && (cls != clsm2);
    const bool valid   = lane < 2 * tl + 1;
    const bool valid64 = (2 * tl + 1) > 64;    // is state 64 valid

    // alpha0: only s=0 (blank) and s=1 (first label, if tl>0) are live.
    float a = NEGV, b = NEGV;                  // a = alpha[lane], b = alpha[64] (lane 63)
    if (lane == 0) a = lds[0];
    if (lane == 1 && tl > 0) a = lds[1];

    // Depth-4 register ring: pf[j] holds step t+j's lp while chunk t runs.
    float pf_s[4], pf_b[4];
    #pragma unroll
    for (int j = 0; j < 4; ++j) {
        pf_s[j] = lds[(1 + j) * SL_ + slot];
        pf_b[j] = lds[(1 + j) * SL_];
    }
    // Steps 1..256 in 64 chunks of 4. Step 256 is a dummy (tt < pl is false
    // with pl<=T_, so its result — computed from padded/garbage lp — is
    // discarded by the cndmask). Prefetch indices stay inside the padded lds.
    for (int t = 1; t <= T_; t += 4) {
        #pragma unroll
        for (int j = 0; j < 4; ++j) {
            const float lp_s = pf_s[j];
            const float lp64 = pf_b[j];
            pf_s[j] = lds[(t + 4 + j) * SL_ + slot];   // prefetch step t+4+j
            pf_b[j] = lds[(t + 4 + j) * SL_];

            const float a2 = dpp_shr1(a, NEGV);        // alpha[lane-1]
            float a3 = dpp_shr1(a2, NEGV);             // alpha[lane-2]
            a3 = skip ? a3 : NEGV;
            // 3-way logsumexp, one log on the chain:
            const float m3 = fmaxf(fmaxf(a, a2), a3);
            const float comb = m3 + __logf(__expf(a - m3) + __expf(a2 - m3)
                                           + __expf(a3 - m3));
            // state 64 (only lane 63's value is meaningful):
            const float nb = valid64 ? (lae2(b, a) + lp64) : NEGV;
            const float na = valid ? (comb + lp_s) : NEGV;
            const int tt = t + j;
            if (tt < pl) { a = na; b = nb; }           // wave-uniform predicate
        }
    }

    const float a_last = (ends >= 64) ? __shfl(b, 63) : __shfl(a, ends);
    float a_prev = __shfl(a, (ends > 0) ? (ends - 1) : 0);
    if (tl <= 0) a_prev = NEGV;
    float nll = -lae2(a_last, a_prev);
    if (!(isfinite(nll) && nll < 1e29f)) nll = 0.f;
    if (lane == 0) partial[n] = nll / (float)((tl > 0) ? tl : 1);

    // Last-block-done mean reduction (release: store+fence+atomic; acquire:
    // fence after observing the final count). atomicAdd is device-scope.
    __threadfence();
    int done = 0;
    if (lane == 0) done = atomicAdd(counter, 1);
    done = __shfl(done, 0);
    if (done == N_ - 1) {
        __threadfence();
        float v = partial[lane];               // lane n reads partial[n]
        v = wred_sum(v);
        if (lane == 0) out[0] = v * (1.0f / (float)N_);
    }
}

extern "C" void kernel_launch(void* const* d_in, const int* in_sizes, int n_in,
                              void* d_out, int out_size, void* d_ws, size_t ws_size,
                              hipStream_t stream) {
    const float* preds   = (const float*)d_in[0];
    const int*   targets = (const int*)d_in[1];
    const int*   plen    = (const int*)d_in[2];
    const int*   tlen    = (const int*)d_in[3];

    float* lp      = (float*)d_ws;                    // N*T*33 floats = 2.16 MB
    float* partial = lp + (size_t)N_ * T_ * SL_;      // +64 floats
    int*   counter = (int*)(partial + N_);            // +1 int

    k_row_lse<<<T_ * N_, 256, 0, stream>>>(preds, targets, lp, counter);
    k_ctc_scan<<<N_, 256, 0, stream>>>(lp, targets, plen, tlen, partial,
                                       counter, (float*)d_out);
}